// Round 1
// baseline (1196.098 us; speedup 1.0000x reference)
//
#include <hip/hip_runtime.h>
#include <hip/hip_bf16.h>

typedef __attribute__((ext_vector_type(8))) short bf16x8;
typedef __attribute__((ext_vector_type(4))) float f32x4;
typedef __attribute__((ext_vector_type(8))) unsigned short u16x8;
typedef __attribute__((ext_vector_type(4))) short s16x4;

__device__ inline short f2b(float f) {
    union { float f; unsigned u; } c;
    c.f = f;
    unsigned r = c.u + 0x7fffu + ((c.u >> 16) & 1u);  // RNE
    return (short)(r >> 16);
}

// ---------------------------------------------------------------------------
// K1: QK[m, 0:1536] = X[m, 0:768] @ W[0:768, 0:1536] + b  (bf16 out, f32 acc)
// 128x128 tile, BK=64, 4 waves (2x2), mfma_f32_16x16x32_bf16.
// LDS rows XOR-swizzled: elem k ^= (row&7)<<3 (16B-slot swizzle).
// ---------------------------------------------------------------------------
__global__ __launch_bounds__(256) void k_gemm_qk(
    const float* __restrict__ X, const float* __restrict__ Wm,
    const float* __restrict__ bias, unsigned short* __restrict__ QK)
{
    __shared__ short As[128 * 64];   // As[row][k]   = X tile
    __shared__ short Bs[128 * 64];   // Bs[n][k]     = W[k][n0+n] (transposed)
    const int tid = threadIdx.x;
    const int lane = tid & 63, wid = tid >> 6;
    const int wrow = wid >> 1, wcol = wid & 1;
    const int l15 = lane & 15, lg = lane >> 4;
    const int m0 = blockIdx.x * 128;
    const int n0 = blockIdx.y * 128;

    f32x4 acc[4][4] = {};

    for (int kt = 0; kt < 768; kt += 64) {
        // stage A: 128x64 f32 -> bf16
#pragma unroll
        for (int i = 0; i < 8; ++i) {
            int f = tid + 256 * i;
            int row = f >> 4, c4 = f & 15;
            float4 v = *(const float4*)(X + (size_t)(m0 + row) * 768 + kt + c4 * 4);
            s16x4 h;
            h[0] = f2b(v.x); h[1] = f2b(v.y); h[2] = f2b(v.z); h[3] = f2b(v.w);
            int idx = row * 64 + ((c4 * 4) ^ ((row & 7) << 3));
            *(s16x4*)(As + idx) = h;
        }
        // stage B transposed: W[kt+kr][n0 + 4*c4 + j] -> Bs[n][kr]
#pragma unroll
        for (int i = 0; i < 8; ++i) {
            int f = tid + 256 * i;
            int kr = f >> 5, c4 = f & 31;
            float4 v = *(const float4*)(Wm + (size_t)(kt + kr) * 2304 + n0 + c4 * 4);
            int n = c4 * 4;
            Bs[(n + 0) * 64 + (kr ^ (((n + 0) & 7) << 3))] = f2b(v.x);
            Bs[(n + 1) * 64 + (kr ^ (((n + 1) & 7) << 3))] = f2b(v.y);
            Bs[(n + 2) * 64 + (kr ^ (((n + 2) & 7) << 3))] = f2b(v.z);
            Bs[(n + 3) * 64 + (kr ^ (((n + 3) & 7) << 3))] = f2b(v.w);
        }
        __syncthreads();
#pragma unroll
        for (int kk = 0; kk < 64; kk += 32) {
            bf16x8 af[4], bfr[4];
#pragma unroll
            for (int m = 0; m < 4; ++m) {
                int r = wrow * 64 + m * 16 + l15;
                af[m] = *(const bf16x8*)(As + r * 64 + ((kk + lg * 8) ^ ((r & 7) << 3)));
            }
#pragma unroll
            for (int n = 0; n < 4; ++n) {
                int r = wcol * 64 + n * 16 + l15;
                bfr[n] = *(const bf16x8*)(Bs + r * 64 + ((kk + lg * 8) ^ ((r & 7) << 3)));
            }
#pragma unroll
            for (int m = 0; m < 4; ++m)
#pragma unroll
                for (int n = 0; n < 4; ++n)
                    acc[m][n] = __builtin_amdgcn_mfma_f32_16x16x32_bf16(
                        af[m], bfr[n], acc[m][n], 0, 0, 0);
        }
        __syncthreads();
    }
    // epilogue: +bias, bf16 store. D layout: col = lane&15, row = (lane>>4)*4 + j
#pragma unroll
    for (int n = 0; n < 4; ++n) {
        int col = n0 + wcol * 64 + n * 16 + l15;
        float bv = bias[col];
#pragma unroll
        for (int m = 0; m < 4; ++m) {
#pragma unroll
            for (int j = 0; j < 4; ++j) {
                int row = m0 + wrow * 64 + m * 16 + lg * 4 + j;
                QK[(size_t)row * 1536 + col] = (unsigned short)f2b(acc[m][n][j] + bv);
            }
        }
    }
}

// ---------------------------------------------------------------------------
// K2: one block per batch.
// Phase 1: A[t][s] = sum_h sigmoid(q_h[t]·k_h[s]/8) for s<t; +12 on diag.
// Phase 2: Y = A @ Z  (12 d-tiles of 64, z converted to bf16 transposed).
// ---------------------------------------------------------------------------
__global__ __launch_bounds__(256) void k_attn(
    const unsigned short* __restrict__ QK, const float* __restrict__ Z,
    float* __restrict__ Y)
{
    __shared__ short qs[128 * 64];    // qs[t][c]
    __shared__ short ks[128 * 64];    // ks[s][c]
    __shared__ short As2[128 * 128];  // A[t][s] bf16
    __shared__ short zs[64 * 128];    // zs[d][s] = z[s][dt+d] bf16
    const int b = blockIdx.x;
    const int tid = threadIdx.x;
    const int lane = tid & 63, wid = tid >> 6;
    const int wrow = wid >> 1, wcol = wid & 1;
    const int l15 = lane & 15, lg = lane >> 4;
    const unsigned short* qk = QK + (size_t)b * 128 * 1536;

    float Aacc[4][4][4] = {};   // [m][n][j]

    for (int h = 0; h < 12; ++h) {
        // stage q_h, k_h (each 128x64 bf16, already bf16 in ws)
#pragma unroll
        for (int i = 0; i < 4; ++i) {
            int f = tid + 256 * i;
            int row = f >> 3, c8 = f & 7;
            u16x8 vq = *(const u16x8*)(qk + (size_t)row * 1536 + h * 64 + c8 * 8);
            u16x8 vk = *(const u16x8*)(qk + (size_t)row * 1536 + 768 + h * 64 + c8 * 8);
            int idx = row * 64 + ((c8 * 8) ^ ((row & 7) << 3));
            *(u16x8*)(qs + idx) = vq;
            *(u16x8*)(ks + idx) = vk;
        }
        __syncthreads();
#pragma unroll
        for (int m = 0; m < 4; ++m) {
#pragma unroll
            for (int n = 0; n < 4; ++n) {
                f32x4 s = {};
#pragma unroll
                for (int kk = 0; kk < 64; kk += 32) {
                    int rq = wrow * 64 + m * 16 + l15;
                    int rk = wcol * 64 + n * 16 + l15;
                    bf16x8 aq = *(const bf16x8*)(qs + rq * 64 + ((kk + lg * 8) ^ ((rq & 7) << 3)));
                    bf16x8 bk = *(const bf16x8*)(ks + rk * 64 + ((kk + lg * 8) ^ ((rk & 7) << 3)));
                    s = __builtin_amdgcn_mfma_f32_16x16x32_bf16(aq, bk, s, 0, 0, 0);
                }
#pragma unroll
                for (int j = 0; j < 4; ++j) {
                    int t = wrow * 64 + m * 16 + lg * 4 + j;
                    int sc = wcol * 64 + n * 16 + l15;
                    if (sc < t) {
                        float v = s[j] * 0.125f;
                        Aacc[m][n][j] += 1.0f / (1.0f + __expf(-v));
                    }
                }
            }
        }
        __syncthreads();
    }
    // A -> LDS (bf16), add 12*I
#pragma unroll
    for (int m = 0; m < 4; ++m)
#pragma unroll
        for (int n = 0; n < 4; ++n)
#pragma unroll
            for (int j = 0; j < 4; ++j) {
                int t = wrow * 64 + m * 16 + lg * 4 + j;
                int sc = wcol * 64 + n * 16 + l15;
                float val = Aacc[m][n][j] + (t == sc ? 12.0f : 0.0f);
                As2[t * 128 + (sc ^ ((t & 7) << 3))] = f2b(val);
            }
    __syncthreads();

    const float* z = Z + (size_t)b * 128 * 768;
    float* y = Y + (size_t)b * 128 * 768;
    for (int dt = 0; dt < 768; dt += 64) {
        // stage z tile transposed: zs[d][s] = z[s][dt+d]
#pragma unroll
        for (int i = 0; i < 8; ++i) {
            int f = tid + 256 * i;
            int srow = f >> 4, c4 = f & 15;
            float4 v = *(const float4*)(z + (size_t)srow * 768 + dt + c4 * 4);
            int d = c4 * 4;
            zs[(d + 0) * 128 + (srow ^ (((d + 0) & 7) << 3))] = f2b(v.x);
            zs[(d + 1) * 128 + (srow ^ (((d + 1) & 7) << 3))] = f2b(v.y);
            zs[(d + 2) * 128 + (srow ^ (((d + 2) & 7) << 3))] = f2b(v.z);
            zs[(d + 3) * 128 + (srow ^ (((d + 3) & 7) << 3))] = f2b(v.w);
        }
        __syncthreads();
        f32x4 o[4][2] = {};
#pragma unroll
        for (int kk = 0; kk < 128; kk += 32) {
            bf16x8 af[4], bz[2];
#pragma unroll
            for (int m = 0; m < 4; ++m) {
                int t = wrow * 64 + m * 16 + l15;
                af[m] = *(const bf16x8*)(As2 + t * 128 + ((kk + lg * 8) ^ ((t & 7) << 3)));
            }
#pragma unroll
            for (int n = 0; n < 2; ++n) {
                int d = wcol * 32 + n * 16 + l15;
                bz[n] = *(const bf16x8*)(zs + d * 128 + ((kk + lg * 8) ^ ((d & 7) << 3)));
            }
#pragma unroll
            for (int m = 0; m < 4; ++m)
#pragma unroll
                for (int n = 0; n < 2; ++n)
                    o[m][n] = __builtin_amdgcn_mfma_f32_16x16x32_bf16(
                        af[m], bz[n], o[m][n], 0, 0, 0);
        }
#pragma unroll
        for (int m = 0; m < 4; ++m)
#pragma unroll
            for (int n = 0; n < 2; ++n)
#pragma unroll
                for (int j = 0; j < 4; ++j) {
                    int t = wrow * 64 + m * 16 + lg * 4 + j;
                    int d = dt + wcol * 32 + n * 16 + l15;
                    y[(size_t)t * 768 + d] = o[m][n][j];
                }
        __syncthreads();
    }
}

extern "C" void kernel_launch(void* const* d_in, const int* in_sizes, int n_in,
                              void* d_out, int out_size, void* d_ws, size_t ws_size,
                              hipStream_t stream) {
    const float* x = (const float*)d_in[0];
    const float* z = (const float*)d_in[1];
    const float* W = (const float*)d_in[2];
    const float* bias = (const float*)d_in[3];
    float* y = (float*)d_out;
    unsigned short* qk = (unsigned short*)d_ws;

    const int B = 512, T = 128;
    const size_t per_b = (size_t)T * 1536 * sizeof(short);  // 384 KiB / batch
    int bs = (int)(ws_size / per_b);
    if (bs < 1) bs = 1;
    if (bs > B) bs = B;

    for (int b0 = 0; b0 < B; b0 += bs) {
        int nb = (B - b0) < bs ? (B - b0) : bs;
        dim3 g1(nb, 12);  // nb*128 rows / 128, 1536 cols / 128
        k_gemm_qk<<<g1, 256, 0, stream>>>(x + (size_t)b0 * T * 768, W, bias, qk);
        k_attn<<<nb, 256, 0, stream>>>(qk, z + (size_t)b0 * T * 768,
                                       y + (size_t)b0 * T * 768);
    }
}

// Round 2
// 846.349 us; speedup vs baseline: 1.4132x; 1.4132x over previous
//
#include <hip/hip_runtime.h>
#include <hip/hip_bf16.h>

typedef __attribute__((ext_vector_type(8))) short bf16x8;
typedef __attribute__((ext_vector_type(4))) float f32x4;
typedef __attribute__((ext_vector_type(8))) unsigned short u16x8;

__device__ __forceinline__ short f2b(float f) {
    union { float f; unsigned u; } c;
    c.f = f;
    unsigned r = c.u + 0x7fffu + ((c.u >> 16) & 1u);  // RNE
    return (short)(r >> 16);
}

__device__ __forceinline__ void glds16(const unsigned short* g, short* l) {
    __builtin_amdgcn_global_load_lds(
        (const __attribute__((address_space(1))) void*)g,
        (__attribute__((address_space(3))) void*)l, 16, 0, 0);
}

// ---------------------------------------------------------------------------
// K0a: convert f32 -> bf16, 8 elems/thread
// ---------------------------------------------------------------------------
__global__ __launch_bounds__(256) void k_cvt(
    const float* __restrict__ in, unsigned short* __restrict__ out, int n8)
{
    int i = blockIdx.x * 256 + threadIdx.x;
    if (i >= n8) return;
    float4 a = ((const float4*)in)[2 * i];
    float4 b = ((const float4*)in)[2 * i + 1];
    u16x8 r;
    r[0] = (unsigned short)f2b(a.x); r[1] = (unsigned short)f2b(a.y);
    r[2] = (unsigned short)f2b(a.z); r[3] = (unsigned short)f2b(a.w);
    r[4] = (unsigned short)f2b(b.x); r[5] = (unsigned short)f2b(b.y);
    r[6] = (unsigned short)f2b(b.z); r[7] = (unsigned short)f2b(b.w);
    ((u16x8*)out)[i] = r;
}

// ---------------------------------------------------------------------------
// K0b: transpose+convert: in[R][C] f32 (row stride rs) -> out[C][R] bf16,
// per batch (blockIdx.x). 64x64 tiles via LDS.
// ---------------------------------------------------------------------------
__global__ __launch_bounds__(256) void k_tcvt(
    const float* __restrict__ in, unsigned short* __restrict__ out,
    int R, int C, int rs, long ibs, long obs)
{
    __shared__ unsigned short t[64][72];
    const float* ib = in + (long)blockIdx.x * ibs;
    unsigned short* ob = out + (long)blockIdx.x * obs;
    int ctiles = C >> 6;
    int r0 = (blockIdx.y / ctiles) * 64, c0 = (blockIdx.y % ctiles) * 64;
    int tid = threadIdx.x;
#pragma unroll
    for (int i = 0; i < 4; ++i) {
        int f = tid + 256 * i;
        int r = f >> 4, c4 = f & 15;
        float4 v = *(const float4*)(ib + (long)(r0 + r) * rs + c0 + c4 * 4);
        t[r][c4 * 4 + 0] = (unsigned short)f2b(v.x);
        t[r][c4 * 4 + 1] = (unsigned short)f2b(v.y);
        t[r][c4 * 4 + 2] = (unsigned short)f2b(v.z);
        t[r][c4 * 4 + 3] = (unsigned short)f2b(v.w);
    }
    __syncthreads();
#pragma unroll
    for (int i = 0; i < 2; ++i) {
        int f = tid + 256 * i;
        int rr = f >> 3, cg = f & 7;
        u16x8 o;
#pragma unroll
        for (int j = 0; j < 8; ++j) o[j] = t[cg * 8 + j][rr];
        *(u16x8*)(ob + (long)(c0 + rr) * R + r0 + cg * 8) = o;
    }
}

// ---------------------------------------------------------------------------
// K1: QK[m, 0:1536] = Xb[m, :] @ Wt[n, :]^T + b   (bf16 in/out, f32 acc)
// 128x128 tile, BK=64, 4 waves (2x2), global_load_lds staging with
// pre-swizzled global source (LDS linear), XOR-swizzled ds_read_b128.
// Bijective XCD swizzle groups the 12 n-blocks of an m-panel on one XCD.
// ---------------------------------------------------------------------------
__global__ __launch_bounds__(256) void k_gemm(
    const unsigned short* __restrict__ Xb, const unsigned short* __restrict__ Wt,
    const float* __restrict__ bias, unsigned short* __restrict__ QK, int nwg)
{
    __shared__ short As[128 * 64];
    __shared__ short Bs[128 * 64];
    const int orig = blockIdx.x;
    const int q8 = nwg >> 3, r8 = nwg & 7;
    const int xcd = orig & 7, jj0 = orig >> 3;
    const int wg = (xcd < r8 ? xcd * (q8 + 1) : r8 * (q8 + 1) + (xcd - r8) * q8) + jj0;
    const int m0 = (wg / 12) * 128;
    const int n0 = (wg % 12) * 128;
    const int tid = threadIdx.x, lane = tid & 63, w = tid >> 6;
    const int wrow = w >> 1, wcol = w & 1, l15 = lane & 15, lg = lane >> 4;

    f32x4 acc[4][4] = {};

    for (int kt = 0; kt < 768; kt += 64) {
#pragma unroll
        for (int i = 0; i < 4; ++i) {
            int f = i * 256 + w * 64 + lane;
            int row = f >> 3, sl = f & 7;
            glds16(Xb + (size_t)(m0 + row) * 768 + kt + 8 * (sl ^ (row & 7)),
                   As + (i * 256 + w * 64) * 8);
            glds16(Wt + (size_t)(n0 + row) * 768 + kt + 8 * (sl ^ (row & 7)),
                   Bs + (i * 256 + w * 64) * 8);
        }
        __syncthreads();
#pragma unroll
        for (int kk = 0; kk < 64; kk += 32) {
            bf16x8 a[4], b[4];
#pragma unroll
            for (int m = 0; m < 4; ++m) {
                int r = wrow * 64 + m * 16 + l15;
                a[m] = *(const bf16x8*)(As + r * 64 + ((kk + lg * 8) ^ ((r & 7) << 3)));
            }
#pragma unroll
            for (int n = 0; n < 4; ++n) {
                int r = wcol * 64 + n * 16 + l15;
                b[n] = *(const bf16x8*)(Bs + r * 64 + ((kk + lg * 8) ^ ((r & 7) << 3)));
            }
#pragma unroll
            for (int m = 0; m < 4; ++m)
#pragma unroll
                for (int n = 0; n < 4; ++n)
                    acc[m][n] = __builtin_amdgcn_mfma_f32_16x16x32_bf16(
                        a[m], b[n], acc[m][n], 0, 0, 0);
        }
        __syncthreads();
    }
#pragma unroll
    for (int n = 0; n < 4; ++n) {
        int col = n0 + wcol * 64 + n * 16 + l15;
        float bv = bias[col];
#pragma unroll
        for (int m = 0; m < 4; ++m)
#pragma unroll
            for (int j = 0; j < 4; ++j) {
                int row = m0 + wrow * 64 + m * 16 + lg * 4 + j;
                QK[(size_t)row * 1536 + col] = (unsigned short)f2b(acc[m][n][j] + bv);
            }
    }
}

// ---------------------------------------------------------------------------
// K2: one block per batch.
// Phase 1: A[t][s] = sum_h sigmoid(q_h[t]·k_h[s]/8), s<t; +12 on diag.
// Phase 2: Y = A @ Z via zT (pre-transposed bf16 [768][128]).
// ---------------------------------------------------------------------------
__global__ __launch_bounds__(256) void k_attn(
    const unsigned short* __restrict__ QK, const unsigned short* __restrict__ ZT,
    float* __restrict__ Y)
{
    __shared__ short qs[128 * 64];
    __shared__ short ks[128 * 64];
    __shared__ short zs[64 * 128];
    __shared__ short As2[128 * 128];
    const int b = blockIdx.x;
    const unsigned short* qk = QK + (size_t)b * 128 * 1536;
    const unsigned short* zt = ZT + (size_t)b * 768 * 128;
    float* y = Y + (size_t)b * 128 * 768;
    const int tid = threadIdx.x, lane = tid & 63, w = tid >> 6;
    const int wrow = w >> 1, wcol = w & 1, l15 = lane & 15, lg = lane >> 4;

    float Aacc[4][4][4] = {};

    for (int h = 0; h < 12; ++h) {
#pragma unroll
        for (int i = 0; i < 4; ++i) {
            int f = i * 256 + w * 64 + lane;
            int row = f >> 3, sl = f & 7;
            const unsigned short* gq = qk + (size_t)row * 1536 + h * 64 + 8 * (sl ^ (row & 7));
            glds16(gq, qs + (i * 256 + w * 64) * 8);
            glds16(gq + 768, ks + (i * 256 + w * 64) * 8);
        }
        __syncthreads();
        f32x4 s[4][4] = {};
#pragma unroll
        for (int kk = 0; kk < 64; kk += 32) {
            bf16x8 a[4], bk[4];
#pragma unroll
            for (int m = 0; m < 4; ++m) {
                int r = wrow * 64 + m * 16 + l15;
                a[m] = *(const bf16x8*)(qs + r * 64 + ((kk + lg * 8) ^ ((r & 7) << 3)));
            }
#pragma unroll
            for (int n = 0; n < 4; ++n) {
                int r = wcol * 64 + n * 16 + l15;
                bk[n] = *(const bf16x8*)(ks + r * 64 + ((kk + lg * 8) ^ ((r & 7) << 3)));
            }
#pragma unroll
            for (int m = 0; m < 4; ++m)
#pragma unroll
                for (int n = 0; n < 4; ++n)
                    s[m][n] = __builtin_amdgcn_mfma_f32_16x16x32_bf16(
                        a[m], bk[n], s[m][n], 0, 0, 0);
        }
#pragma unroll
        for (int m = 0; m < 4; ++m)
#pragma unroll
            for (int n = 0; n < 4; ++n) {
                int sc = wcol * 64 + n * 16 + l15;
                int tb = wrow * 64 + m * 16 + lg * 4;
#pragma unroll
                for (int j = 0; j < 4; ++j) {
                    float sig = __builtin_amdgcn_rcpf(1.0f + __expf(-0.125f * s[m][n][j]));
                    Aacc[m][n][j] += (sc < tb + j) ? sig : 0.0f;
                }
            }
        __syncthreads();
    }
#pragma unroll
    for (int m = 0; m < 4; ++m)
#pragma unroll
        for (int n = 0; n < 4; ++n)
#pragma unroll
            for (int j = 0; j < 4; ++j) {
                int t = wrow * 64 + m * 16 + lg * 4 + j;
                int sc = wcol * 64 + n * 16 + l15;
                float val = Aacc[m][n][j] + (t == sc ? 12.0f : 0.0f);
                As2[t * 128 + (sc ^ ((t & 7) << 3))] = f2b(val);
            }
    __syncthreads();

    for (int dt = 0; dt < 768; dt += 64) {
#pragma unroll
        for (int i = 0; i < 4; ++i) {
            int f = i * 256 + w * 64 + lane;
            int row = f >> 4, sl = f & 15;
            glds16(zt + (size_t)(dt + row) * 128 + 8 * (sl ^ (row & 7)),
                   zs + (i * 256 + w * 64) * 8);
        }
        __syncthreads();
        f32x4 o[4][2] = {};
#pragma unroll
        for (int kk = 0; kk < 128; kk += 32) {
            bf16x8 a[4], bz[2];
#pragma unroll
            for (int m = 0; m < 4; ++m) {
                int t = wrow * 64 + m * 16 + l15;
                a[m] = *(const bf16x8*)(As2 + t * 128 + ((kk + lg * 8) ^ ((t & 7) << 3)));
            }
#pragma unroll
            for (int n = 0; n < 2; ++n) {
                int d = wcol * 32 + n * 16 + l15;
                bz[n] = *(const bf16x8*)(zs + d * 128 + ((kk + lg * 8) ^ ((d & 7) << 3)));
            }
#pragma unroll
            for (int m = 0; m < 4; ++m)
#pragma unroll
                for (int n = 0; n < 2; ++n)
                    o[m][n] = __builtin_amdgcn_mfma_f32_16x16x32_bf16(
                        a[m], bz[n], o[m][n], 0, 0, 0);
        }
#pragma unroll
        for (int m = 0; m < 4; ++m)
#pragma unroll
            for (int n = 0; n < 2; ++n)
#pragma unroll
                for (int j = 0; j < 4; ++j) {
                    int t = wrow * 64 + m * 16 + lg * 4 + j;
                    int d = dt + wcol * 32 + n * 16 + l15;
                    y[(size_t)t * 768 + d] = o[m][n][j];
                }
        __syncthreads();
    }
}

extern "C" void kernel_launch(void* const* d_in, const int* in_sizes, int n_in,
                              void* d_out, int out_size, void* d_ws, size_t ws_size,
                              hipStream_t stream) {
    const float* x = (const float*)d_in[0];
    const float* z = (const float*)d_in[1];
    const float* W = (const float*)d_in[2];
    const float* bias = (const float*)d_in[3];
    float* y = (float*)d_out;

    const int B = 512, T = 128;
    char* ws = (char*)d_ws;
    const size_t wt_bytes = (size_t)1536 * 768 * 2;          // 2.36 MB
    unsigned short* Wt = (unsigned short*)ws;
    char* p = ws + wt_bytes;

    const size_t xsz = (size_t)T * 768;    // elems per batch (bf16)
    const size_t zsz = (size_t)768 * T;
    const size_t qsz = (size_t)T * 1536;
    const size_t per_b = (xsz + zsz + qsz) * 2;              // 768 KB/batch
    int bs = (int)((ws_size - wt_bytes) / per_b);
    if (bs < 1) bs = 1;
    if (bs > B) bs = B;

    unsigned short* xb = (unsigned short*)p;
    unsigned short* zT = xb + xsz * bs;
    unsigned short* qk = zT + zsz * bs;

    // W[0:768, 0:1536] -> Wt[1536][768] bf16
    k_tcvt<<<dim3(1, 288), 256, 0, stream>>>(W, Wt, 768, 1536, 2304, 0, 0);

    for (int b0 = 0; b0 < B; b0 += bs) {
        int nb = (B - b0) < bs ? (B - b0) : bs;
        int n8 = nb * T * 768 / 8;
        k_cvt<<<(n8 + 255) / 256, 256, 0, stream>>>(x + (size_t)b0 * T * 768, xb, n8);
        k_tcvt<<<dim3(nb, 24), 256, 0, stream>>>(z + (size_t)b0 * T * 768, zT,
                                                 128, 768, 768,
                                                 (long)T * 768, (long)768 * T);
        int nwg = nb * 12;
        k_gemm<<<nwg, 256, 0, stream>>>(xb, Wt, bias, qk, nwg);
        k_attn<<<nb, 256, 0, stream>>>(qk, zT, y + (size_t)b0 * T * 768);
    }
}